// Round 11
// baseline (261.463 us; speedup 1.0000x reference)
//
#include <hip/hip_runtime.h>
#include <hip/hip_bf16.h>
#include <stdint.h>

// Problem constants
#define B_    2
#define S_    2048
#define D_    1024
#define H_    16
#define NTOK  (B_ * S_)   // 4096

typedef __attribute__((ext_vector_type(8))) short bf16x8;
typedef __attribute__((ext_vector_type(4))) float f32x4;
typedef __attribute__((ext_vector_type(16))) float f32x16;
typedef __attribute__((ext_vector_type(2))) float float2v;
typedef __attribute__((ext_vector_type(2))) __bf16 bfv2;

// packed pair fp32 -> 2x bf16 (v_cvt_pk_bf16_f32, RNE)
static __device__ __forceinline__ unsigned int pkbf(float a, float b) {
    float2v fv = {a, b};
    bfv2 r = __builtin_convertvector(fv, bfv2);
    unsigned int u;
    __builtin_memcpy(&u, &r, 4);
    return u;
}

// async global->LDS, 16 B per lane; LDS dest = wave-uniform base + lane*16
using g_cu32 = __attribute__((address_space(1))) const unsigned int;
using l_u32  = __attribute__((address_space(3))) unsigned int;
static __device__ __forceinline__ void gld16(const void* g, void* l) {
    __builtin_amdgcn_global_load_lds((g_cu32*)g, (l_u32*)l, 16, 0, 0);
}

// counted vmcnt wait (T4): lets prefetched global_load_lds stay in flight
// across raw s_barrier (no __syncthreads drain).
template<int N> static __device__ __forceinline__ void wait_vm() {
    if constexpr (N == 0)      asm volatile("s_waitcnt vmcnt(0)" ::: "memory");
    else if constexpr (N == 2) asm volatile("s_waitcnt vmcnt(2)" ::: "memory");
    else if constexpr (N == 3) asm volatile("s_waitcnt vmcnt(3)" ::: "memory");
    else if constexpr (N == 4) asm volatile("s_waitcnt vmcnt(4)" ::: "memory");
}

#define QN ((size_t)NTOK * D_)   // 4194304
#define WN ((size_t)D_ * D_)     // 1048576 = 1<<20

struct SwapT { static constexpr bool value = true; };
struct NoSwapT { static constexpr bool value = false; };

// ---------------------------------------------------------------------------
// prep v2: blocks [0,4096) = fp32->bf16 bulk convert, 16 elems/thread;
// blocks [4096,5120) = mask tile flags (flags[qt][kt] = any-zero in 64x64).
// ---------------------------------------------------------------------------
__global__ __launch_bounds__(256) void prep_kernel(
    const float* __restrict__ q, const float* __restrict__ k, const float* __restrict__ v,
    const float* __restrict__ Wq, const float* __restrict__ Wk,
    const float* __restrict__ Wv, const float* __restrict__ Wo,
    const int* __restrict__ mask,
    unsigned short* __restrict__ qb, unsigned short* __restrict__ kb,
    unsigned short* __restrict__ vb, unsigned short* __restrict__ wqb,
    unsigned short* __restrict__ wkb, unsigned short* __restrict__ wvb,
    unsigned short* __restrict__ wob, int* __restrict__ flags) {
    __shared__ int anyz;
    if (blockIdx.x < 4096) {
        size_t i = ((size_t)blockIdx.x * 256 + threadIdx.x) * 16;
        const float* s; unsigned short* d; size_t off;
        if (i < QN)          { s = q; d = qb; off = i; }
        else if (i < 2 * QN) { s = k; d = kb; off = i - QN; }
        else if (i < 3 * QN) { s = v; d = vb; off = i - 2 * QN; }
        else {
            size_t j = i - 3 * QN;
            int wi = (int)(j >> 20);
            s = (wi == 0) ? Wq : (wi == 1) ? Wk : (wi == 2) ? Wv : Wo;
            d = (wi == 0) ? wqb : (wi == 1) ? wkb : (wi == 2) ? wvb : wob;
            off = j & (WN - 1);
        }
        float4 a0 = *(const float4*)(s + off);
        float4 a1 = *(const float4*)(s + off + 4);
        float4 a2 = *(const float4*)(s + off + 8);
        float4 a3 = *(const float4*)(s + off + 12);
        uint4 p0, p1;
        p0.x = pkbf(a0.x, a0.y); p0.y = pkbf(a0.z, a0.w);
        p0.z = pkbf(a1.x, a1.y); p0.w = pkbf(a1.z, a1.w);
        p1.x = pkbf(a2.x, a2.y); p1.y = pkbf(a2.z, a2.w);
        p1.z = pkbf(a3.x, a3.y); p1.w = pkbf(a3.z, a3.w);
        *(uint4*)(d + off)     = p0;
        *(uint4*)(d + off + 8) = p1;
    } else {
        if (threadIdx.x == 0) anyz = 0;
        __syncthreads();
        int bid2 = blockIdx.x - 4096;
        const int qt = bid2 >> 5, kt = bid2 & 31;
        int az = 0;
        for (int i = threadIdx.x; i < 64 * 64; i += 256) {
            int r = i >> 6, c = i & 63;
            az |= (mask[(size_t)(qt * 64 + r) * S_ + kt * 64 + c] == 0) ? 1 : 0;
        }
        if (az) atomicOr(&anyz, 1);
        __syncthreads();
        if (threadIdx.x == 0) flags[qt * 32 + kt] = anyz;
    }
}

// ---------------------------------------------------------------------------
// bf16 GEMM (R3-proven, 57.7 us): C[M,N] = A[M,K] @ W[N,K]^T + bias, *scale.
// BMT x 128 tile, BK=32, 256 thr = 4 waves (2x2), global_load_lds(16B),
// depth-3 counted-vmcnt pipeline (raw s_barrier, no drain in main loop).
// modes: 0 = fp32 out, 1 = bf16 out, 2 = bf16 Vt layout (Vt[(b*H+h)*64+d][s])
// Modes 0/1 run with SWAPPED mfma operands (acc holds C^T fragments).
// ---------------------------------------------------------------------------
struct GemmArgs {
    const unsigned short* A[3];
    const unsigned short* W[3];
    const float* bias[3];
    void* C[3];
    int mode[3];
    float scale[3];
};

template<int BMT>
__global__ __launch_bounds__(256, 3) void gemm_async(GemmArgs ga) {
    constexpr int AG = BMT / 16;   // A groups
    constexpr int MI = BMT / 32;   // acc rows per wave
    constexpr int NK = D_ / 32;    // 32 k-steps
    constexpr int LOADS = (BMT == 128) ? 4 : 3;  // gld16 per wave per stage
    const int z = blockIdx.z;
    const unsigned short* __restrict__ A = ga.A[z];
    const unsigned short* __restrict__ W = ga.W[z];
    const float* __restrict__ bias = ga.bias[z];
    void* C = ga.C[z];
    const int mode = ga.mode[z];
    const float scl = ga.scale[z];

    __shared__ unsigned short As[3][AG * 512];
    __shared__ unsigned short Bs[3][8 * 512];

    const int t    = threadIdx.x;
    const int lane = t & 63;
    const int w    = t >> 6;
    const int fr   = lane & 15;
    const int kq   = lane >> 4;
    const int wrow = w >> 1, wcol = w & 1;
    const int m0 = blockIdx.x * BMT, n0 = blockIdx.y * 128;

    const int sc = lane >> 4;   // chunk
    const int sr = lane & 15;   // row in group

    const unsigned short* ga0;
    const unsigned short* ga1 = nullptr;
    int la0Off, la1Off = 0;
    if constexpr (BMT == 128) {
        ga0 = A + (size_t)(m0 + (2 * w) * 16 + sr) * D_ + sc * 8;
        ga1 = ga0 + 16 * D_;
        la0Off = (2 * w) * 512;
        la1Off = (2 * w + 1) * 512;
    } else {
        ga0 = A + (size_t)(m0 + w * 16 + sr) * D_ + sc * 8;
        la0Off = w * 512;
    }
    const unsigned short* gw0 = W + (size_t)(n0 + (2 * w) * 16 + sr) * D_ + sc * 8;
    const unsigned short* gw1 = gw0 + 16 * D_;
    const int lw0Off = (2 * w) * 512;
    const int lw1Off = (2 * w + 1) * 512;

    int aOff[MI], bOff[4];
#pragma unroll
    for (int mi = 0; mi < MI; ++mi) aOff[mi] = (wrow * MI + mi) * 512 + (kq * 16 + fr) * 8;
#pragma unroll
    for (int ni = 0; ni < 4; ++ni) bOff[ni] = (wcol * 4 + ni) * 512 + (kq * 16 + fr) * 8;

    f32x4 acc[MI][4];
#pragma unroll
    for (int i = 0; i < MI; ++i)
#pragma unroll
        for (int j = 0; j < 4; ++j) acc[i][j] = (f32x4)0.0f;

    auto stage = [&](int buf) {
        gld16(ga0, &As[buf][la0Off]);
        if constexpr (BMT == 128) gld16(ga1, &As[buf][la1Off]);
        gld16(gw0, &Bs[buf][lw0Off]);
        gld16(gw1, &Bs[buf][lw1Off]);
        ga0 += 32; gw0 += 32; gw1 += 32;
        if constexpr (BMT == 128) ga1 += 32;
    };

    auto kloop = [&](auto swc) {
        constexpr bool SW = decltype(swc)::value;
        auto mma_step = [&](int cur) {
            const unsigned short* Ab = As[cur];
            const unsigned short* Bb = Bs[cur];
            bf16x8 af[MI], bfr[4];
#pragma unroll
            for (int mi = 0; mi < MI; ++mi) af[mi] = *(const bf16x8*)&Ab[aOff[mi]];
#pragma unroll
            for (int ni = 0; ni < 4; ++ni) bfr[ni] = *(const bf16x8*)&Bb[bOff[ni]];
#pragma unroll
            for (int mi = 0; mi < MI; ++mi)
#pragma unroll
                for (int ni = 0; ni < 4; ++ni) {
                    if constexpr (SW)
                        acc[mi][ni] = __builtin_amdgcn_mfma_f32_16x16x32_bf16(
                            bfr[ni], af[mi], acc[mi][ni], 0, 0, 0);
                    else
                        acc[mi][ni] = __builtin_amdgcn_mfma_f32_16x16x32_bf16(
                            af[mi], bfr[ni], acc[mi][ni], 0, 0, 0);
                }
        };

        stage(0);               // tile 0 -> buf 0
        stage(1);               // tile 1 -> buf 1
        int cur = 0;
        for (int k0 = 0; k0 < NK - 1; ++k0) {
            __builtin_amdgcn_sched_barrier(0);
            wait_vm<LOADS>();                     // tile k0 resident (own loads)
            __builtin_amdgcn_s_barrier();         // ... for all waves
            __builtin_amdgcn_sched_barrier(0);
            if (k0 + 2 < NK) {
                int pf = (cur >= 1) ? cur - 1 : cur + 2;   // (cur+2)%3
                stage(pf);
            }
            mma_step(cur);
            cur = (cur < 2) ? cur + 1 : 0;
        }
        __builtin_amdgcn_sched_barrier(0);
        wait_vm<0>();                             // final tile: full drain
        __builtin_amdgcn_s_barrier();
        __builtin_amdgcn_sched_barrier(0);
        mma_step(cur);
    };
    if (mode == 2) kloop(NoSwapT{}); else kloop(SwapT{});

    if (mode == 2) {
        // original orientation: row=token=(lane>>4)*4+reg, col=feature=lane&15
        // Vt[((b*H+h)*64+d)*S + s], 4 consecutive s per lane
        unsigned short* Co = (unsigned short*)C;
#pragma unroll
        for (int ni = 0; ni < 4; ++ni) {
            int col = n0 + wcol * 64 + ni * 16 + fr;
            float bv = bias[col];
            int hh = col >> 6, d = col & 63;
#pragma unroll
            for (int mi = 0; mi < MI; ++mi) {
                int tok = m0 + wrow * (BMT / 2) + mi * 16 + kq * 4;
                int bb = tok >> 11, sbase = tok & (S_ - 1);
                uint2 pk;
                pk.x = pkbf((acc[mi][ni][0] + bv) * scl, (acc[mi][ni][1] + bv) * scl);
                pk.y = pkbf((acc[mi][ni][2] + bv) * scl, (acc[mi][ni][3] + bv) * scl);
                *(uint2*)(Co + ((size_t)((bb * H_ + hh) * 64 + d)) * S_ + sbase) = pk;
            }
        }
    } else if (mode == 0) {
        // swapped: row=token=lane&15, 4 consecutive features per lane
        float* Co = (float*)C;
#pragma unroll
        for (int ni = 0; ni < 4; ++ni) {
            int nb = n0 + wcol * 64 + ni * 16 + kq * 4;
            float4 b4 = *(const float4*)&bias[nb];
#pragma unroll
            for (int mi = 0; mi < MI; ++mi) {
                int m = m0 + wrow * (BMT / 2) + mi * 16 + fr;
                float4 o4;
                o4.x = (acc[mi][ni][0] + b4.x) * scl;
                o4.y = (acc[mi][ni][1] + b4.y) * scl;
                o4.z = (acc[mi][ni][2] + b4.z) * scl;
                o4.w = (acc[mi][ni][3] + b4.w) * scl;
                *(float4*)(Co + (size_t)m * D_ + nb) = o4;
            }
        }
    } else {
        unsigned short* Co = (unsigned short*)C;
#pragma unroll
        for (int ni = 0; ni < 4; ++ni) {
            int nb = n0 + wcol * 64 + ni * 16 + kq * 4;
            float4 b4 = *(const float4*)&bias[nb];
#pragma unroll
            for (int mi = 0; mi < MI; ++mi) {
                int m = m0 + wrow * (BMT / 2) + mi * 16 + fr;
                uint2 pk;
                pk.x = pkbf((acc[mi][ni][0] + b4.x) * scl, (acc[mi][ni][1] + b4.y) * scl);
                pk.y = pkbf((acc[mi][ni][2] + b4.z) * scl, (acc[mi][ni][3] + b4.w) * scl);
                *(uint2*)(Co + (size_t)m * D_ + nb) = pk;
            }
        }
    }
}

// ---------------------------------------------------------------------------
// MFMA flash attention v9: v6 geometry (8 waves, 128 q-rows, grid 512,
// 2 blocks/CU, 64 KB LDS, depth-3 counted-vmcnt ring) with 32x32x16 MFMA.
// Mechanism: each 1 KB LDS A-frag now feeds 16384 MACs (vs 8192 at 16x16),
// halving A-frag LDS bytes/FLOP at UNCHANGED geometry (v7/v8 showed geometry
// deviations regress). Per-lane LDS reads/step: 288 B -> 192 B.
// Wave w = (kg=w>>2, qc=w&3): QK^T computes keys kg*32..+32 x q qc*32..+32
// (4 chained K=16 MFMAs over d); PV computes d kg*32..+32 x same q over all
// 64 keys (4 MFMAs). P crosses waves via XOR-swizzled Ps[128][64] with one
// extra lgkmcnt(0)+s_barrier per step. l needs an end-of-kernel cross-kg
// LDS combine (Ps reused as the 1 KB float buffer).
// K/V LDS: 8 subtiles/tile x 1 KB; subtile s=w staged by wave w with the
// per-lane global source arranged so ds_read_b128 at base+lane*16 IS the
// A-frag (row=lane&31, k=(lane>>5)*8+j) -> conflict-free reads.
// C/D map (m74/m101): col=lane&31, row=(reg&3)+8*(reg>>2)+4*(lane>>5).
// ---------------------------------------------------------------------------
__global__ __launch_bounds__(512, 4) void flash4(
    const unsigned short* __restrict__ Qb, const unsigned short* __restrict__ Kb,
    const unsigned short* __restrict__ Vtg, const int* __restrict__ mask,
    const int* __restrict__ flags, unsigned short* __restrict__ Xb) {
    __shared__ unsigned short Ks[3][4096];
    __shared__ unsigned short Vs[3][4096];
    __shared__ unsigned short Ps[8192];   // [128 q][64 keys] bf16, XOR-swizzled

    const int t    = threadIdx.x;
    const int lane = t & 63;
    const int w    = t >> 6;     // wave 0..7
    const int r31  = lane & 31;
    const int hi   = lane >> 5;  // 0/1
    const int qc   = w & 3;      // q column group (32 q)
    const int kg   = w >> 2;     // QK key-group / PV d-group
    // XCD-chunked swizzle (nwg=512, 64/XCD)
    const int bid = blockIdx.x;
    const int swb = ((bid & 7) << 6) | (bid >> 3);
    const int qt = swb & 15, hd = (swb >> 4) & 15, b = swb >> 8;
    const int q0 = qt * 128;
    const int qloc = qc * 32 + r31;        // local q row 0..127
    const int qglob = q0 + qloc;

    // Q B-frags: frag t covers d = t*16 + hi*8 .. +8 (col=lane&31=q)
    const unsigned short* qrow_p = Qb + (size_t)(b * S_ + qglob) * D_ + hd * 64;
    bf16x8 qfr[4];
#pragma unroll
    for (int tt = 0; tt < 4; ++tt)
        qfr[tt] = *(const bf16x8*)(qrow_p + tt * 16 + hi * 8);

    // wave's 64-row flag tile = qt*2 + (qc>>1) -> bitmask over kt
    int fl = (lane < 32) ? flags[(qt * 2 + (qc >> 1)) * 32 + lane] : 0;
    unsigned int fmask = (unsigned int)__ballot(fl != 0);

    // staging: wave w fills K subtile w (keys (w>>2)*32+r31, d (w&3)*16+hi*8)
    // and V subtile w (d rows (w>>2)*32+r31, keys (w&3)*16+hi*8), 1 gld16 each.
    const unsigned short* kptr =
        Kb + (size_t)(b * S_ + kg * 32 + r31) * D_ + hd * 64 + qc * 16 + hi * 8;
    const unsigned short* vptr =
        Vtg + ((size_t)((b * H_ + hd) * 64 + kg * 32 + r31)) * S_ + qc * 16 + hi * 8;

    auto stageKV = [&](int buf, const unsigned short* kp, const unsigned short* vp) {
        gld16(kp, (char*)&Ks[buf][0] + w * 1024);
        gld16(vp, (char*)&Vs[buf][0] + w * 1024);
    };

    // prologue: tiles 0,1 into bufs 0,1
    stageKV(0, kptr, vptr);
    stageKV(1, kptr + (size_t)64 * D_, vptr + 64);
    const unsigned short* kpf = kptr + (size_t)128 * D_;
    const unsigned short* vpf = vptr + 128;

    // Ps byte offsets (XOR-swizzle ((q&7)<<4) kills the 128 B row-stride conflict)
    const int qx = (qloc & 7) << 4;
    int psw[4], psr[4];
#pragma unroll
    for (int t2 = 0; t2 < 4; ++t2)
        psw[t2] = (qloc << 7) + ((kg * 64 + hi * 8 + t2 * 16) ^ qx);   // 8 B uint2
#pragma unroll
    for (int c = 0; c < 4; ++c)
        psr[c] = (qloc << 7) + ((c * 32 + hi * 16) ^ qx);              // 16 B frag

    const f32x16 zf16 = (f32x16)0.0f;
    f32x16 o = zf16;
    float2v l2 = {0.0f, 0.0f};

    auto attn_step = [&](int cur, int kt) {
        const char* ksb = (const char*)&Ks[cur][0];
        const char* vsb = (const char*)&Vs[cur][0];
        const int lb = lane * 16;

        // S^T = K . Q^T over d: 4 chained K=16 MFMAs; D[key][q], col=q
        f32x16 st;
        {
            bf16x8 kf = *(const bf16x8*)(ksb + ((kg * 4 + 0) << 10) + lb);
            st = __builtin_amdgcn_mfma_f32_32x32x16_bf16(kf, qfr[0], zf16, 0, 0, 0);
        }
#pragma unroll
        for (int tt = 1; tt < 4; ++tt) {
            bf16x8 kf = *(const bf16x8*)(ksb + ((kg * 4 + tt) << 10) + lb);
            st = __builtin_amdgcn_mfma_f32_32x32x16_bf16(kf, qfr[tt], st, 0, 0, 0);
        }

        if ((fmask >> kt) & 1u) {
            // lane's q = qglob; reg 4*t2+j -> key = kt*64 + kg*32 + 8*t2 + 4*hi + j
#pragma unroll
            for (int t2 = 0; t2 < 4; ++t2) {
                int4 mv = *(const int4*)&mask[(size_t)qglob * S_ + kt * 64 +
                                              kg * 32 + t2 * 8 + hi * 4];
                if (mv.x == 0) st[4 * t2 + 0] = -3e8f;
                if (mv.y == 0) st[4 * t2 + 1] = -3e8f;
                if (mv.z == 0) st[4 * t2 + 2] = -3e8f;
                if (mv.w == 0) st[4 * t2 + 3] = -3e8f;
            }
        }

        // P = exp2(s), accumulate l, pack bf16 into swizzled Ps
#pragma unroll
        for (int t2 = 0; t2 < 4; ++t2) {
            float e0 = __builtin_amdgcn_exp2f(st[4 * t2 + 0]);
            float e1 = __builtin_amdgcn_exp2f(st[4 * t2 + 1]);
            float e2 = __builtin_amdgcn_exp2f(st[4 * t2 + 2]);
            float e3 = __builtin_amdgcn_exp2f(st[4 * t2 + 3]);
            l2 += (float2v){e0, e1} + (float2v){e2, e3};
            uint2 pk;
            pk.x = pkbf(e0, e1);
            pk.y = pkbf(e2, e3);
            *(uint2*)((char*)Ps + psw[t2]) = pk;
        }

        // P now crosses waves: drain own ds_writes, barrier, then PV
        asm volatile("s_waitcnt lgkmcnt(0)" ::: "memory");
        __builtin_amdgcn_sched_barrier(0);
        __builtin_amdgcn_s_barrier();
        __builtin_amdgcn_sched_barrier(0);

        // O^T += Vt . P^T : 4 MFMAs over 64 keys (K=16 each); D[d][q]
#pragma unroll
        for (int c = 0; c < 4; ++c) {
            bf16x8 vf = *(const bf16x8*)(vsb + ((kg * 4 + c) << 10) + lb);
            bf16x8 pb = *(const bf16x8*)((const char*)Ps + psr[c]);
            o = __builtin_amdgcn_mfma_f32_32x32x16_bf16(vf, pb, o, 0, 0, 0);
        }
    };

    int cur = 0;
    for (int kt = 0; kt < 31; ++kt) {
        __builtin_amdgcn_sched_barrier(0);
        wait_vm<2>();                       // tile kt resident (own 2 loads)
        __builtin_amdgcn_s_barrier();       // ... for all waves
        __builtin_amdgcn_sched_barrier(0);
        if (kt < 30) {
            int pf = (cur >= 1) ? cur - 1 : cur + 2;   // (cur+2)%3
            stageKV(pf, kpf, vpf);
            kpf += (size_t)64 * D_;
            vpf += 64;
        }
        attn_step(cur, kt);
        cur = (cur < 2) ? cur + 1 : 0;
    }
    __builtin_amdgcn_sched_barrier(0);
    wait_vm<0>();                           // last tile: full drain
    __builtin_amdgcn_s_barrier();
    __builtin_amdgcn_sched_barrier(0);
    attn_step(cur, 31);

    // l: lane partial covers its kg's 16 key-rows; + lane^32 = full kg sum;
    // combine across kg (waves qc and qc+4) via LDS (reuse Ps).
    float l_loc = l2.x + l2.y;
    l_loc += __shfl_xor(l_loc, 32, 64);
    __syncthreads();                       // all PV reads of Ps complete
    float* Lf = (float*)Ps;
    Lf[qloc * 2 + kg] = l_loc;             // dup writes (lane, lane^32) benign
    __syncthreads();
    float rl = 1.0f / (Lf[qloc * 2] + Lf[qloc * 2 + 1]);

    // X write: lane's 16 values = d rows kg*32 + 4*hi + 8*t2 + j, one q col
    unsigned short* xrow = Xb + (size_t)(b * S_ + qglob) * D_ + hd * 64;
#pragma unroll
    for (int t2 = 0; t2 < 4; ++t2) {
        uint2 pk;
        pk.x = pkbf(o[4 * t2 + 0] * rl, o[4 * t2 + 1] * rl);
        pk.y = pkbf(o[4 * t2 + 2] * rl, o[4 * t2 + 3] * rl);
        *(uint2*)(xrow + kg * 32 + t2 * 8 + hi * 4) = pk;
    }
}

// ---------------------------------------------------------------------------
extern "C" void kernel_launch(void* const* d_in, const int* in_sizes, int n_in,
                              void* d_out, int out_size, void* d_ws, size_t ws_size,
                              hipStream_t stream) {
    const float* q    = (const float*)d_in[0];
    const float* k    = (const float*)d_in[1];
    const float* v    = (const float*)d_in[2];
    const int*   mask = (const int*)d_in[3];
    const float* Wq   = (const float*)d_in[4];
    const float* bq   = (const float*)d_in[5];
    const float* Wk   = (const float*)d_in[6];
    const float* bk   = (const float*)d_in[7];
    const float* Wv   = (const float*)d_in[8];
    const float* bv   = (const float*)d_in[9];
    const float* Wo   = (const float*)d_in[10];
    const float* bo   = (const float*)d_in[11];
    float* out = (float*)d_out;

    // workspace (shorts): qb kb vb | Qf Kf Vt | wqb wkb wvb wob | flags  (~59 MB)
    unsigned short* qb  = (unsigned short*)d_ws;
    unsigned short* kb  = qb + QN;
    unsigned short* vb  = kb + QN;
    unsigned short* Qf  = vb + QN;
    unsigned short* Kf  = Qf + QN;
    unsigned short* Vt  = Kf + QN;
    unsigned short* wqb = Vt + QN;
    unsigned short* wkb = wqb + WN;
    unsigned short* wvb = wkb + WN;
    unsigned short* wob = wvb + WN;
    int* flags = (int*)(wob + WN);

    const float SC = 0.18033688011112042f;  // (1/8) * log2(e)

    prep_kernel<<<5120, 256, 0, stream>>>(q, k, v, Wq, Wk, Wv, Wo, mask,
                                          qb, kb, vb, wqb, wkb, wvb, wob, flags);

    GemmArgs g1;
    g1.A[0] = qb;  g1.W[0] = wqb; g1.bias[0] = bq; g1.C[0] = Qf; g1.mode[0] = 1; g1.scale[0] = SC;
    g1.A[1] = kb;  g1.W[1] = wkb; g1.bias[1] = bk; g1.C[1] = Kf; g1.mode[1] = 1; g1.scale[1] = 1.0f;
    g1.A[2] = vb;  g1.W[2] = wvb; g1.bias[2] = bv; g1.C[2] = Vt; g1.mode[2] = 2; g1.scale[2] = 1.0f;
    gemm_async<128><<<dim3(NTOK / 128, D_ / 128, 3), 256, 0, stream>>>(g1);

    flash4<<<dim3((S_ / 128) * H_ * B_, 1, 1), 512, 0, stream>>>(Qf, Kf, Vt, mask, flags, Qf);

    GemmArgs g2;
    g2.A[0] = Qf; g2.W[0] = wob; g2.bias[0] = bo; g2.C[0] = out; g2.mode[0] = 0; g2.scale[0] = 1.0f;
    g2.A[1] = g2.A[2] = nullptr; g2.W[1] = g2.W[2] = nullptr;
    g2.bias[1] = g2.bias[2] = nullptr; g2.C[1] = g2.C[2] = nullptr;
    g2.mode[1] = g2.mode[2] = 0; g2.scale[1] = g2.scale[2] = 1.0f;
    gemm_async<64><<<dim3(NTOK / 64, D_ / 128, 1), 256, 0, stream>>>(g2);
}